// Round 1
// baseline (456.377 us; speedup 1.0000x reference)
//
#include <hip/hip_runtime.h>

#define N_NODES 50000
#define D 64

// ---------------------------------------------------------------------------
// 0. dtype probe: edge_index may be int64 (ref says so) or int32 (JAX x64-off
//    demotion). For int64 with values < 2^31, every odd 32-bit word is 0.
// ---------------------------------------------------------------------------
__global__ void detect_kernel(const unsigned* __restrict__ ei32, int* flag) {
    if (threadIdx.x == 0 && blockIdx.x == 0) {
        int is64 = 1;
        for (int i = 0; i < 32; ++i) {
            if (ei32[2 * i + 1] != 0u) { is64 = 0; break; }
        }
        *flag = is64;
    }
}

__device__ __forceinline__ int load_src(const unsigned* ei32, int is64, int E, int e) {
    return is64 ? (int)ei32[2 * e] : (int)ei32[e];
}
__device__ __forceinline__ int load_dst(const unsigned* ei32, int is64, int E, int e) {
    return is64 ? (int)ei32[2 * (E + e)] : (int)ei32[E + e];
}

// ---------------------------------------------------------------------------
// 1. histogram of dst
// ---------------------------------------------------------------------------
__global__ __launch_bounds__(256) void hist_kernel(const unsigned* __restrict__ ei32,
                                                   const int* __restrict__ flag,
                                                   int E, int* __restrict__ cnt) {
    int e = blockIdx.x * 256 + threadIdx.x;
    if (e >= E) return;
    int is64 = *flag;
    int d = load_dst(ei32, is64, E, e);
    atomicAdd(&cnt[d], 1);
}

// ---------------------------------------------------------------------------
// 2. exclusive scan (single block, 1024 threads, chunked Hillis-Steele)
//    writes row_ptr[0..n] and cursor[0..n-1]
// ---------------------------------------------------------------------------
__global__ __launch_bounds__(1024) void scan_kernel(const int* __restrict__ cnt,
                                                    int* __restrict__ rp,
                                                    int* __restrict__ cursor, int n) {
    __shared__ int buf[1024];
    __shared__ int s_running;
    int tid = threadIdx.x;
    if (tid == 0) s_running = 0;
    __syncthreads();
    for (int base = 0; base < n; base += 1024) {
        int i = base + tid;
        int v = (i < n) ? cnt[i] : 0;
        buf[tid] = v;
        __syncthreads();
        for (int off = 1; off < 1024; off <<= 1) {
            int t = (tid >= off) ? buf[tid - off] : 0;
            __syncthreads();
            buf[tid] += t;
            __syncthreads();
        }
        int incl = buf[tid];
        int excl = incl - v;
        int run = s_running;
        __syncthreads();
        if (i < n) { rp[i] = run + excl; cursor[i] = run + excl; }
        if (tid == 1023) s_running = run + incl;
        __syncthreads();
    }
    if (tid == 0) rp[n] = s_running;
}

// ---------------------------------------------------------------------------
// 3. scatter src into CSR order
// ---------------------------------------------------------------------------
__global__ __launch_bounds__(256) void scatter_kernel(const unsigned* __restrict__ ei32,
                                                      const int* __restrict__ flag,
                                                      int E, int* __restrict__ cursor,
                                                      int* __restrict__ ssrc) {
    int e = blockIdx.x * 256 + threadIdx.x;
    if (e >= E) return;
    int is64 = *flag;
    int s = load_src(ei32, is64, E, e);
    int d = load_dst(ei32, is64, E, e);
    int pos = atomicAdd(&cursor[d], 1);
    ssrc[pos] = s;
}

// ---------------------------------------------------------------------------
// 4. fused layer: mean-aggregate + (agg @ Wl^T + bl + x @ Wr^T) [+ relu]
//    block = 256 threads = 4 waves = 4 nodes; lane = feature/output dim.
// ---------------------------------------------------------------------------
template <bool RELU>
__global__ __launch_bounds__(256) void sage_layer(const float* __restrict__ xin,
                                                  const int* __restrict__ rp,
                                                  const int* __restrict__ ssrc,
                                                  const float* __restrict__ Wl,
                                                  const float* __restrict__ bl,
                                                  const float* __restrict__ Wr,
                                                  float* __restrict__ out, int n) {
    __shared__ float sWl[64][65];   // +1 pad: lane-varying row index -> no conflicts
    __shared__ float sWr[64][65];
    __shared__ float sAgg[4][64];
    __shared__ float sX[4][64];

    int tid = threadIdx.x;
    for (int i = tid; i < 64 * 64; i += 256) {
        int r = i >> 6, c = i & 63;
        sWl[r][c] = Wl[i];
        sWr[r][c] = Wr[i];
    }

    int wave = tid >> 6;
    int lane = tid & 63;
    int node = blockIdx.x * 4 + wave;

    if (node < n) {
        int beg = rp[node], end = rp[node + 1];
        float acc = 0.f;
        int e = beg;
        // 4x unroll: keep 4 gather chains in flight
        for (; e + 3 < end; e += 4) {
            int s0 = ssrc[e], s1 = ssrc[e + 1], s2 = ssrc[e + 2], s3 = ssrc[e + 3];
            float v0 = xin[s0 * 64 + lane];
            float v1 = xin[s1 * 64 + lane];
            float v2 = xin[s2 * 64 + lane];
            float v3 = xin[s3 * 64 + lane];
            acc += (v0 + v1) + (v2 + v3);
        }
        for (; e < end; ++e) acc += xin[ssrc[e] * 64 + lane];
        int deg = end - beg;
        float inv = 1.0f / (float)(deg > 1 ? deg : 1);
        sAgg[wave][lane] = acc * inv;
        sX[wave][lane] = xin[node * 64 + lane];
    }
    __syncthreads();

    if (node < n) {
        int o = lane;
        float accl = 0.f, accr = 0.f;
#pragma unroll
        for (int k = 0; k < 64; ++k) {
            accl += sAgg[wave][k] * sWl[o][k];   // sAgg[wave][k]: uniform addr -> broadcast
            accr += sX[wave][k] * sWr[o][k];
        }
        float r = bl[o] + accl + accr;
        if (RELU) r = fmaxf(r, 0.f);
        out[node * 64 + o] = r;
    }
}

// ---------------------------------------------------------------------------
extern "C" void kernel_launch(void* const* d_in, const int* in_sizes, int n_in,
                              void* d_out, int out_size, void* d_ws, size_t ws_size,
                              hipStream_t stream) {
    const float* x      = (const float*)d_in[0];
    const unsigned* ei  = (const unsigned*)d_in[1];
    const float* Wl0    = (const float*)d_in[2];
    const float* bl0    = (const float*)d_in[3];
    const float* Wr0    = (const float*)d_in[4];
    const float* Wl1    = (const float*)d_in[5];
    const float* bl1    = (const float*)d_in[6];
    const float* Wr1    = (const float*)d_in[7];
    float* out          = (float*)d_out;

    const int N = N_NODES;
    const int E = in_sizes[1] / 2;

    // workspace layout (256B aligned chunks)
    char* w = (char*)d_ws;
    auto take = [&](size_t bytes) {
        char* p = w;
        w += (bytes + 255) & ~(size_t)255;
        return p;
    };
    int*   flag   = (int*)take(sizeof(int));
    int*   cnt    = (int*)take((size_t)N * sizeof(int));
    int*   rp     = (int*)take((size_t)(N + 1) * sizeof(int));
    int*   cursor = (int*)take((size_t)N * sizeof(int));
    int*   ssrc   = (int*)take((size_t)E * sizeof(int));
    float* h0     = (float*)take((size_t)N * D * sizeof(float));

    hipMemsetAsync(cnt, 0, (size_t)N * sizeof(int), stream);
    detect_kernel<<<1, 64, 0, stream>>>(ei, flag);
    hist_kernel<<<(E + 255) / 256, 256, 0, stream>>>(ei, flag, E, cnt);
    scan_kernel<<<1, 1024, 0, stream>>>(cnt, rp, cursor, N);
    scatter_kernel<<<(E + 255) / 256, 256, 0, stream>>>(ei, flag, E, cursor, ssrc);

    int blocks = (N + 3) / 4;
    sage_layer<true><<<blocks, 256, 0, stream>>>(x, rp, ssrc, Wl0, bl0, Wr0, h0, N);
    sage_layer<false><<<blocks, 256, 0, stream>>>(h0, rp, ssrc, Wl1, bl1, Wr1, out, N);
}

// Round 2
// 403.464 us; speedup vs baseline: 1.1311x; 1.1311x over previous
//
#include <hip/hip_runtime.h>

#define N_NODES 50000
#define D 64

typedef __attribute__((ext_vector_type(4))) float f4;

// ---------------------------------------------------------------------------
// 0. dtype probe: edge_index may be int64 (ref) or int32 (JAX x64-off).
//    Node ids < 50000, so for int64 every odd 32-bit word is 0.
//    Parallel: 64 lanes check one word each, ballot.
// ---------------------------------------------------------------------------
__global__ void detect_kernel(const unsigned* __restrict__ ei32, int* __restrict__ flag) {
    int tid = threadIdx.x;
    unsigned v = ei32[2 * tid + 1];
    unsigned long long m = __ballot(v != 0u);
    if (tid == 0) *flag = (m == 0ull) ? 1 : 0;
}

__device__ __forceinline__ int load_src(const unsigned* ei32, int is64, int E, int e) {
    return is64 ? (int)ei32[2 * e] : (int)ei32[e];
}
__device__ __forceinline__ int load_dst(const unsigned* ei32, int is64, int E, int e) {
    return is64 ? (int)ei32[2 * (E + e)] : (int)ei32[E + e];
}

// ---------------------------------------------------------------------------
// 1. histogram of dst
// ---------------------------------------------------------------------------
__global__ __launch_bounds__(256) void hist_kernel(const unsigned* __restrict__ ei32,
                                                   const int* __restrict__ flag,
                                                   int E, int* __restrict__ cnt) {
    int e = blockIdx.x * 256 + threadIdx.x;
    if (e >= E) return;
    int is64 = *flag;
    atomicAdd(&cnt[load_dst(ei32, is64, E, e)], 1);
}

// ---------------------------------------------------------------------------
// 2. three-kernel exclusive scan over cnt[0..n) -> rp, cursor; rp[n]=total
// ---------------------------------------------------------------------------
__global__ __launch_bounds__(256) void scan_partial(const int* __restrict__ cnt,
                                                    int* __restrict__ bsum, int n) {
    __shared__ int ws4[4];
    int i = blockIdx.x * 256 + threadIdx.x;
    int v = (i < n) ? cnt[i] : 0;
#pragma unroll
    for (int off = 1; off < 64; off <<= 1) v += __shfl_xor(v, off);
    int wave = threadIdx.x >> 6, lane = threadIdx.x & 63;
    if (lane == 0) ws4[wave] = v;
    __syncthreads();
    if (threadIdx.x == 0) bsum[blockIdx.x] = ws4[0] + ws4[1] + ws4[2] + ws4[3];
}

__global__ __launch_bounds__(256) void scan_bsums(const int* __restrict__ bsum,
                                                  int* __restrict__ boff,
                                                  int* __restrict__ rp, int nb, int n) {
    __shared__ int sb[256];
    int tid = threadIdx.x;
    int v = (tid < nb) ? bsum[tid] : 0;
    sb[tid] = v;
    __syncthreads();
    for (int off = 1; off < 256; off <<= 1) {
        int t = (tid >= off) ? sb[tid - off] : 0;
        __syncthreads();
        sb[tid] += t;
        __syncthreads();
    }
    if (tid < nb) boff[tid] = sb[tid] - v;
    if (tid == 255) rp[n] = sb[255];
}

__global__ __launch_bounds__(256) void scan_final(const int* __restrict__ cnt,
                                                  const int* __restrict__ boff,
                                                  int* __restrict__ rp,
                                                  int* __restrict__ cursor, int n) {
    __shared__ int sb[256];
    int tid = threadIdx.x;
    int i = blockIdx.x * 256 + tid;
    int v = (i < n) ? cnt[i] : 0;
    sb[tid] = v;
    __syncthreads();
    for (int off = 1; off < 256; off <<= 1) {
        int t = (tid >= off) ? sb[tid - off] : 0;
        __syncthreads();
        sb[tid] += t;
        __syncthreads();
    }
    if (i < n) {
        int e = sb[tid] - v + boff[blockIdx.x];
        rp[i] = e;
        cursor[i] = e;
    }
}

// ---------------------------------------------------------------------------
// 3. scatter src into CSR order
// ---------------------------------------------------------------------------
__global__ __launch_bounds__(256) void scatter_kernel(const unsigned* __restrict__ ei32,
                                                      const int* __restrict__ flag,
                                                      int E, int* __restrict__ cursor,
                                                      int* __restrict__ ssrc) {
    int e = blockIdx.x * 256 + threadIdx.x;
    if (e >= E) return;
    int is64 = *flag;
    int s = load_src(ei32, is64, E, e);
    int d = load_dst(ei32, is64, E, e);
    int pos = atomicAdd(&cursor[d], 1);
    ssrc[pos] = s;
}

// ---------------------------------------------------------------------------
// 4a. aggregation: wave per node, float4 gather (lane = (row r, chunk c)),
//     4 edges per load-instruction, 8 in flight; shfl_xor cross-group reduce.
//     No LDS -> 32 waves/CU for latency hiding.
// ---------------------------------------------------------------------------
__global__ __launch_bounds__(256) void agg_kernel(const float* __restrict__ xin,
                                                  const int* __restrict__ rp,
                                                  const int* __restrict__ ssrc,
                                                  float* __restrict__ agg, int n) {
    int gw = (blockIdx.x * 256 + threadIdx.x) >> 6;   // global wave id = node
    if (gw >= n) return;
    int lane = threadIdx.x & 63;
    int r = lane >> 4;        // edge slot 0..3
    int c = lane & 15;        // float4 chunk 0..15
    int beg = rp[gw], end = rp[gw + 1];
    f4 acc0 = {0.f, 0.f, 0.f, 0.f};
    f4 acc1 = {0.f, 0.f, 0.f, 0.f};
    for (int e = beg + r; e < end; e += 8) {
        int s = ssrc[e];
        acc0 += *(const f4*)&xin[s * 64 + c * 4];
        int e1 = e + 4;
        if (e1 < end) {
            int s1 = ssrc[e1];
            acc1 += *(const f4*)&xin[s1 * 64 + c * 4];
        }
    }
    f4 acc = acc0 + acc1;
#pragma unroll
    for (int i = 0; i < 4; ++i) {
        float t = acc[i];
        t += __shfl_xor(t, 16);
        t += __shfl_xor(t, 32);
        acc[i] = t;
    }
    int deg = end - beg;
    float inv = 1.0f / (float)(deg > 1 ? deg : 1);
    if (r == 0) *(f4*)&agg[gw * 64 + c * 4] = acc * inv;
}

// ---------------------------------------------------------------------------
// 4b. linear: out[n][o] = agg[n] . Wl[o] + x[n] . Wr[o] + bl[o] (+relu)
//     lane o holds Wl[o][:], Wr[o][:] in 128 VGPRs. agg/x rows loaded once
//     per node (coalesced 16 x float4, 4-way replicated), broadcast via shfl.
//     Pure-VALU matmul -> uses all 4 SIMDs, no LDS pipe contention.
// ---------------------------------------------------------------------------
template <bool RELU>
__global__ __launch_bounds__(256) void lin_kernel(const float* __restrict__ aggp,
                                                  const float* __restrict__ xin,
                                                  const float* __restrict__ Wl,
                                                  const float* __restrict__ bl,
                                                  const float* __restrict__ Wr,
                                                  float* __restrict__ out, int n) {
    int lane = threadIdx.x & 63;
    int c = lane & 15;
    f4 wl[16], wr[16];
#pragma unroll
    for (int k = 0; k < 16; ++k) {
        wl[k] = *(const f4*)&Wl[lane * 64 + k * 4];
        wr[k] = *(const f4*)&Wr[lane * 64 + k * 4];
    }
    float b = bl[lane];
    int gw = (blockIdx.x * 256 + threadIdx.x) >> 6;
    int nw = gridDim.x * 4;
    for (int node = gw; node < n; node += nw) {
        f4 a = *(const f4*)&aggp[node * 64 + c * 4];
        f4 x = *(const f4*)&xin[node * 64 + c * 4];
        float accl0 = 0.f, accl1 = 0.f, accr0 = 0.f, accr1 = 0.f;
#pragma unroll
        for (int k = 0; k < 16; k += 2) {
            f4 a4, x4, a5, x5;
#pragma unroll
            for (int j = 0; j < 4; ++j) {
                a4[j] = __shfl(a[j], k);
                x4[j] = __shfl(x[j], k);
                a5[j] = __shfl(a[j], k + 1);
                x5[j] = __shfl(x[j], k + 1);
            }
            accl0 += a4[0] * wl[k][0] + a4[1] * wl[k][1] + a4[2] * wl[k][2] + a4[3] * wl[k][3];
            accr0 += x4[0] * wr[k][0] + x4[1] * wr[k][1] + x4[2] * wr[k][2] + x4[3] * wr[k][3];
            accl1 += a5[0] * wl[k + 1][0] + a5[1] * wl[k + 1][1] + a5[2] * wl[k + 1][2] + a5[3] * wl[k + 1][3];
            accr1 += x5[0] * wr[k + 1][0] + x5[1] * wr[k + 1][1] + x5[2] * wr[k + 1][2] + x5[3] * wr[k + 1][3];
        }
        float res = (accl0 + accl1) + (accr0 + accr1) + b;
        if (RELU) res = fmaxf(res, 0.f);
        out[node * 64 + lane] = res;
    }
}

// ---------------------------------------------------------------------------
extern "C" void kernel_launch(void* const* d_in, const int* in_sizes, int n_in,
                              void* d_out, int out_size, void* d_ws, size_t ws_size,
                              hipStream_t stream) {
    const float* x      = (const float*)d_in[0];
    const unsigned* ei  = (const unsigned*)d_in[1];
    const float* Wl0    = (const float*)d_in[2];
    const float* bl0    = (const float*)d_in[3];
    const float* Wr0    = (const float*)d_in[4];
    const float* Wl1    = (const float*)d_in[5];
    const float* bl1    = (const float*)d_in[6];
    const float* Wr1    = (const float*)d_in[7];
    float* out          = (float*)d_out;

    const int N = N_NODES;
    const int E = in_sizes[1] / 2;
    const int NB = (N + 255) / 256;   // 196 scan blocks

    char* w = (char*)d_ws;
    size_t used = 0;
    auto take = [&](size_t bytes) {
        char* p = w;
        size_t a = (bytes + 255) & ~(size_t)255;
        w += a; used += a;
        return p;
    };
    int*   flag   = (int*)take(sizeof(int));
    int*   cnt    = (int*)take((size_t)N * sizeof(int));
    int*   rp     = (int*)take((size_t)(N + 1) * sizeof(int));
    int*   cursor = (int*)take((size_t)N * sizeof(int));
    int*   ssrc   = (int*)take((size_t)E * sizeof(int));
    int*   bsum   = (int*)take((size_t)NB * sizeof(int));
    int*   boff   = (int*)take((size_t)NB * sizeof(int));
    float* agg    = (float*)take((size_t)N * D * sizeof(float));
    // h0: prefer workspace; fall back to in-place in d_out (row-wise safe)
    float* h0;
    if (used + (size_t)N * D * sizeof(float) <= ws_size) {
        h0 = (float*)take((size_t)N * D * sizeof(float));
    } else {
        h0 = out;
    }

    hipMemsetAsync(cnt, 0, (size_t)N * sizeof(int), stream);
    detect_kernel<<<1, 64, 0, stream>>>(ei, flag);
    hist_kernel<<<(E + 255) / 256, 256, 0, stream>>>(ei, flag, E, cnt);
    scan_partial<<<NB, 256, 0, stream>>>(cnt, bsum, N);
    scan_bsums<<<1, 256, 0, stream>>>(bsum, boff, rp, NB, N);
    scan_final<<<NB, 256, 0, stream>>>(cnt, boff, rp, cursor, N);
    scatter_kernel<<<(E + 255) / 256, 256, 0, stream>>>(ei, flag, E, cursor, ssrc);

    int aggBlocks = (N * 64 + 255) / 256;   // one wave per node
    agg_kernel<<<aggBlocks, 256, 0, stream>>>(x, rp, ssrc, agg, N);
    lin_kernel<true><<<512, 256, 0, stream>>>(agg, x, Wl0, bl0, Wr0, h0, N);
    agg_kernel<<<aggBlocks, 256, 0, stream>>>(h0, rp, ssrc, agg, N);
    lin_kernel<false><<<512, 256, 0, stream>>>(agg, h0, Wl1, bl1, Wr1, out, N);
}

// Round 3
// 297.929 us; speedup vs baseline: 1.5318x; 1.3542x over previous
//
#include <hip/hip_runtime.h>

#define N_NODES 50000
#define D 64

typedef __attribute__((ext_vector_type(4))) float f4;

// ---------------------------------------------------------------------------
// 0. dtype probe: edge_index may be int64 (ref) or int32 (JAX x64-off).
//    Node ids < 50000, so for int64 every odd 32-bit word is 0.
// ---------------------------------------------------------------------------
__global__ void detect_kernel(const unsigned* __restrict__ ei32, int* __restrict__ flag) {
    int tid = threadIdx.x;
    unsigned v = ei32[2 * tid + 1];
    unsigned long long m = __ballot(v != 0u);
    if (tid == 0) *flag = (m == 0ull) ? 1 : 0;
}

__device__ __forceinline__ int load_src(const unsigned* ei32, int is64, int E, int e) {
    return is64 ? (int)ei32[2 * e] : (int)ei32[e];
}
__device__ __forceinline__ int load_dst(const unsigned* ei32, int is64, int E, int e) {
    return is64 ? (int)ei32[2 * (E + e)] : (int)ei32[E + e];
}

// ---------------------------------------------------------------------------
// 1. histogram of dst
// ---------------------------------------------------------------------------
__global__ __launch_bounds__(256) void hist_kernel(const unsigned* __restrict__ ei32,
                                                   const int* __restrict__ flag,
                                                   int E, int* __restrict__ cnt) {
    int e = blockIdx.x * 256 + threadIdx.x;
    if (e >= E) return;
    int is64 = *flag;
    atomicAdd(&cnt[load_dst(ei32, is64, E, e)], 1);
}

// ---------------------------------------------------------------------------
// 2. three-kernel exclusive scan over cnt[0..n) -> rp, cursor; rp[n]=total
// ---------------------------------------------------------------------------
__global__ __launch_bounds__(256) void scan_partial(const int* __restrict__ cnt,
                                                    int* __restrict__ bsum, int n) {
    __shared__ int ws4[4];
    int i = blockIdx.x * 256 + threadIdx.x;
    int v = (i < n) ? cnt[i] : 0;
#pragma unroll
    for (int off = 1; off < 64; off <<= 1) v += __shfl_xor(v, off);
    int wave = threadIdx.x >> 6, lane = threadIdx.x & 63;
    if (lane == 0) ws4[wave] = v;
    __syncthreads();
    if (threadIdx.x == 0) bsum[blockIdx.x] = ws4[0] + ws4[1] + ws4[2] + ws4[3];
}

__global__ __launch_bounds__(256) void scan_bsums(const int* __restrict__ bsum,
                                                  int* __restrict__ boff,
                                                  int* __restrict__ rp, int nb, int n) {
    __shared__ int sb[256];
    int tid = threadIdx.x;
    int v = (tid < nb) ? bsum[tid] : 0;
    sb[tid] = v;
    __syncthreads();
    for (int off = 1; off < 256; off <<= 1) {
        int t = (tid >= off) ? sb[tid - off] : 0;
        __syncthreads();
        sb[tid] += t;
        __syncthreads();
    }
    if (tid < nb) boff[tid] = sb[tid] - v;
    if (tid == 255) rp[n] = sb[255];
}

__global__ __launch_bounds__(256) void scan_final(const int* __restrict__ cnt,
                                                  const int* __restrict__ boff,
                                                  int* __restrict__ rp,
                                                  int* __restrict__ cursor, int n) {
    __shared__ int sb[256];
    int tid = threadIdx.x;
    int i = blockIdx.x * 256 + tid;
    int v = (i < n) ? cnt[i] : 0;
    sb[tid] = v;
    __syncthreads();
    for (int off = 1; off < 256; off <<= 1) {
        int t = (tid >= off) ? sb[tid - off] : 0;
        __syncthreads();
        sb[tid] += t;
        __syncthreads();
    }
    if (i < n) {
        int e = sb[tid] - v + boff[blockIdx.x];
        rp[i] = e;
        cursor[i] = e;
    }
}

// ---------------------------------------------------------------------------
// 3. scatter src into CSR order
// ---------------------------------------------------------------------------
__global__ __launch_bounds__(256) void scatter_kernel(const unsigned* __restrict__ ei32,
                                                      const int* __restrict__ flag,
                                                      int E, int* __restrict__ cursor,
                                                      int* __restrict__ ssrc) {
    int e = blockIdx.x * 256 + threadIdx.x;
    if (e >= E) return;
    int is64 = *flag;
    int s = load_src(ei32, is64, E, e);
    int d = load_dst(ei32, is64, E, e);
    int pos = atomicAdd(&cursor[d], 1);
    ssrc[pos] = s;
}

// ---------------------------------------------------------------------------
// 4a. aggregation: wave per node, float4 gather (lane = (slot r, chunk c)),
//     4 edges per load-instruction, 8 in flight; shfl_xor cross-group reduce.
//     No LDS -> full occupancy for latency hiding.
// ---------------------------------------------------------------------------
__global__ __launch_bounds__(256) void agg_kernel(const float* __restrict__ xin,
                                                  const int* __restrict__ rp,
                                                  const int* __restrict__ ssrc,
                                                  float* __restrict__ agg, int n) {
    int gw = (blockIdx.x * 256 + threadIdx.x) >> 6;   // global wave id = node
    if (gw >= n) return;
    int lane = threadIdx.x & 63;
    int r = lane >> 4;        // edge slot 0..3
    int c = lane & 15;        // float4 chunk 0..15
    int beg = rp[gw], end = rp[gw + 1];
    f4 acc0 = {0.f, 0.f, 0.f, 0.f};
    f4 acc1 = {0.f, 0.f, 0.f, 0.f};
    for (int e = beg + r; e < end; e += 8) {
        int s = ssrc[e];
        acc0 += *(const f4*)&xin[s * 64 + c * 4];
        int e1 = e + 4;
        if (e1 < end) {
            int s1 = ssrc[e1];
            acc1 += *(const f4*)&xin[s1 * 64 + c * 4];
        }
    }
    f4 acc = acc0 + acc1;
#pragma unroll
    for (int i = 0; i < 4; ++i) {
        float t = acc[i];
        t += __shfl_xor(t, 16);
        t += __shfl_xor(t, 32);
        acc[i] = t;
    }
    int deg = end - beg;
    float inv = 1.0f / (float)(deg > 1 ? deg : 1);
    if (r == 0) *(f4*)&agg[gw * 64 + c * 4] = acc * inv;
}

// ---------------------------------------------------------------------------
// 4b. linear: out[n][o] = agg[n] . Wl[o] + x[n] . Wr[o] + bl[o] (+relu)
//     lane o holds Wl[o][:], Wr[o][:] in 128 VGPRs. Node features are loaded
//     one dword per lane (lane l holds feature l) and broadcast with
//     v_readlane -> SGPR (VALU, no LDS pipe — __shfl would be ds_bpermute!),
//     feeding v_fmac v,s,v. 4 accumulators break the FMA dep chain.
// ---------------------------------------------------------------------------
template <bool RELU>
__global__ __launch_bounds__(256) void lin_kernel(const float* __restrict__ aggp,
                                                  const float* __restrict__ xin,
                                                  const float* __restrict__ Wl,
                                                  const float* __restrict__ bl,
                                                  const float* __restrict__ Wr,
                                                  float* __restrict__ out, int n) {
    int lane = threadIdx.x & 63;
    f4 wl[16], wr[16];
#pragma unroll
    for (int k = 0; k < 16; ++k) {
        wl[k] = *(const f4*)&Wl[lane * 64 + k * 4];
        wr[k] = *(const f4*)&Wr[lane * 64 + k * 4];
    }
    float b = bl[lane];
    int gw = (blockIdx.x * 256 + threadIdx.x) >> 6;
    int nw = gridDim.x * 4;
    for (int node = gw; node < n; node += nw) {
        int ai = __builtin_bit_cast(int, aggp[node * 64 + lane]);
        int xi = __builtin_bit_cast(int, xin[node * 64 + lane]);
        float accl0 = 0.f, accl1 = 0.f, accr0 = 0.f, accr1 = 0.f;
#pragma unroll
        for (int k = 0; k < 64; k += 2) {
            float a0 = __builtin_bit_cast(float, __builtin_amdgcn_readlane(ai, k));
            float x0 = __builtin_bit_cast(float, __builtin_amdgcn_readlane(xi, k));
            float a1 = __builtin_bit_cast(float, __builtin_amdgcn_readlane(ai, k + 1));
            float x1 = __builtin_bit_cast(float, __builtin_amdgcn_readlane(xi, k + 1));
            accl0 = fmaf(a0, wl[k >> 2][k & 3], accl0);
            accr0 = fmaf(x0, wr[k >> 2][k & 3], accr0);
            accl1 = fmaf(a1, wl[(k + 1) >> 2][(k + 1) & 3], accl1);
            accr1 = fmaf(x1, wr[(k + 1) >> 2][(k + 1) & 3], accr1);
        }
        float res = (accl0 + accl1) + (accr0 + accr1) + b;
        if (RELU) res = fmaxf(res, 0.f);
        out[node * 64 + lane] = res;
    }
}

// ---------------------------------------------------------------------------
extern "C" void kernel_launch(void* const* d_in, const int* in_sizes, int n_in,
                              void* d_out, int out_size, void* d_ws, size_t ws_size,
                              hipStream_t stream) {
    const float* x      = (const float*)d_in[0];
    const unsigned* ei  = (const unsigned*)d_in[1];
    const float* Wl0    = (const float*)d_in[2];
    const float* bl0    = (const float*)d_in[3];
    const float* Wr0    = (const float*)d_in[4];
    const float* Wl1    = (const float*)d_in[5];
    const float* bl1    = (const float*)d_in[6];
    const float* Wr1    = (const float*)d_in[7];
    float* out          = (float*)d_out;

    const int N = N_NODES;
    const int E = in_sizes[1] / 2;
    const int NB = (N + 255) / 256;   // 196 scan blocks

    char* w = (char*)d_ws;
    size_t used = 0;
    auto take = [&](size_t bytes) {
        char* p = w;
        size_t a = (bytes + 255) & ~(size_t)255;
        w += a; used += a;
        return p;
    };
    int*   flag   = (int*)take(sizeof(int));
    int*   cnt    = (int*)take((size_t)N * sizeof(int));
    int*   rp     = (int*)take((size_t)(N + 1) * sizeof(int));
    int*   cursor = (int*)take((size_t)N * sizeof(int));
    int*   ssrc   = (int*)take((size_t)E * sizeof(int));
    int*   bsum   = (int*)take((size_t)NB * sizeof(int));
    int*   boff   = (int*)take((size_t)NB * sizeof(int));
    float* agg    = (float*)take((size_t)N * D * sizeof(float));
    // h0: prefer workspace; fall back to in-place in d_out (row-wise safe)
    float* h0;
    if (used + (size_t)N * D * sizeof(float) <= ws_size) {
        h0 = (float*)take((size_t)N * D * sizeof(float));
    } else {
        h0 = out;
    }

    hipMemsetAsync(cnt, 0, (size_t)N * sizeof(int), stream);
    detect_kernel<<<1, 64, 0, stream>>>(ei, flag);
    hist_kernel<<<(E + 255) / 256, 256, 0, stream>>>(ei, flag, E, cnt);
    scan_partial<<<NB, 256, 0, stream>>>(cnt, bsum, N);
    scan_bsums<<<1, 256, 0, stream>>>(bsum, boff, rp, NB, N);
    scan_final<<<NB, 256, 0, stream>>>(cnt, boff, rp, cursor, N);
    scatter_kernel<<<(E + 255) / 256, 256, 0, stream>>>(ei, flag, E, cursor, ssrc);

    int aggBlocks = (N * 64 + 255) / 256;   // one wave per node
    agg_kernel<<<aggBlocks, 256, 0, stream>>>(x, rp, ssrc, agg, N);
    lin_kernel<true><<<1024, 256, 0, stream>>>(agg, x, Wl0, bl0, Wr0, h0, N);
    agg_kernel<<<aggBlocks, 256, 0, stream>>>(h0, rp, ssrc, agg, N);
    lin_kernel<false><<<1024, 256, 0, stream>>>(agg, h0, Wl1, bl1, Wr1, out, N);
}

// Round 4
// 278.284 us; speedup vs baseline: 1.6400x; 1.0706x over previous
//
#include <hip/hip_runtime.h>

#define N_NODES 50000
#define D 64

typedef __attribute__((ext_vector_type(4))) float f4;
typedef __attribute__((ext_vector_type(4))) unsigned uv4;
typedef __attribute__((ext_vector_type(4))) unsigned short us4;

// f32 -> bf16 round-to-nearest-even
static __device__ __forceinline__ unsigned short f2bf(float f) {
    unsigned u = __builtin_bit_cast(unsigned, f);
    unsigned r = (u + 0x7fffu + ((u >> 16) & 1u)) >> 16;
    return (unsigned short)r;
}

// ---------------------------------------------------------------------------
// 0. dtype probe: edge_index may be int64 (ref) or int32 (JAX x64-off).
//    Node ids < 50000, so for int64 every odd 32-bit word is 0.
// ---------------------------------------------------------------------------
__global__ void detect_kernel(const unsigned* __restrict__ ei32, int* __restrict__ flag) {
    int tid = threadIdx.x;
    unsigned v = ei32[2 * tid + 1];
    unsigned long long m = __ballot(v != 0u);
    if (tid == 0) *flag = (m == 0ull) ? 1 : 0;
}

// ---------------------------------------------------------------------------
// 0b. x -> bf16 conversion
// ---------------------------------------------------------------------------
__global__ __launch_bounds__(256) void cvt_kernel(const float* __restrict__ x,
                                                  unsigned short* __restrict__ xb, int total) {
    int i = (blockIdx.x * 256 + threadIdx.x) * 4;
    if (i + 3 < total) {
        f4 v = *(const f4*)&x[i];
        us4 o;
        o[0] = f2bf(v[0]); o[1] = f2bf(v[1]); o[2] = f2bf(v[2]); o[3] = f2bf(v[3]);
        *(us4*)&xb[i] = o;
    } else {
        for (int j = i; j < total; ++j) xb[j] = f2bf(x[j]);
    }
}

// ---------------------------------------------------------------------------
// 1. histogram of dst — 4 edges/thread, uint4 loads
// ---------------------------------------------------------------------------
__global__ __launch_bounds__(256) void hist_kernel(const unsigned* __restrict__ ei32,
                                                   const int* __restrict__ flag,
                                                   int E, int* __restrict__ cnt) {
    int base = (blockIdx.x * 256 + threadIdx.x) * 4;
    if (base >= E) return;
    int is64 = *flag;
    if (base + 3 < E && (E & 3) == 0) {
        int d0, d1, d2, d3;
        if (is64) {
            uv4 a = *(const uv4*)&ei32[2 * (E + base)];
            uv4 b = *(const uv4*)&ei32[2 * (E + base) + 4];
            d0 = (int)a[0]; d1 = (int)a[2]; d2 = (int)b[0]; d3 = (int)b[2];
        } else {
            uv4 a = *(const uv4*)&ei32[E + base];
            d0 = (int)a[0]; d1 = (int)a[1]; d2 = (int)a[2]; d3 = (int)a[3];
        }
        atomicAdd(&cnt[d0], 1); atomicAdd(&cnt[d1], 1);
        atomicAdd(&cnt[d2], 1); atomicAdd(&cnt[d3], 1);
    } else {
        for (int e = base; e < E && e < base + 4; ++e) {
            int d = is64 ? (int)ei32[2 * (E + e)] : (int)ei32[E + e];
            atomicAdd(&cnt[d], 1);
        }
    }
}

// ---------------------------------------------------------------------------
// 2. two-kernel exclusive scan: partial sums, then per-block offset reduce +
//    local scan (nb <= 256 required; nb = 196 here)
// ---------------------------------------------------------------------------
__global__ __launch_bounds__(256) void scan_partial(const int* __restrict__ cnt,
                                                    int* __restrict__ bsum, int n) {
    __shared__ int ws4[4];
    int i = blockIdx.x * 256 + threadIdx.x;
    int v = (i < n) ? cnt[i] : 0;
#pragma unroll
    for (int off = 1; off < 64; off <<= 1) v += __shfl_xor(v, off);
    int wave = threadIdx.x >> 6, lane = threadIdx.x & 63;
    if (lane == 0) ws4[wave] = v;
    __syncthreads();
    if (threadIdx.x == 0) bsum[blockIdx.x] = ws4[0] + ws4[1] + ws4[2] + ws4[3];
}

__global__ __launch_bounds__(256) void scan_final(const int* __restrict__ cnt,
                                                  const int* __restrict__ bsum,
                                                  int* __restrict__ rp,
                                                  int* __restrict__ cursor, int n, int nb) {
    __shared__ int sb[256];
    __shared__ int sOff[4];
    int tid = threadIdx.x;
    // block offset = sum_{j < blockIdx.x} bsum[j]
    int pb = (tid < blockIdx.x && tid < nb) ? bsum[tid] : 0;
#pragma unroll
    for (int off = 1; off < 64; off <<= 1) pb += __shfl_xor(pb, off);
    int wv = tid >> 6, ln = tid & 63;
    if (ln == 0) sOff[wv] = pb;
    __syncthreads();
    int boff = sOff[0] + sOff[1] + sOff[2] + sOff[3];

    int i = blockIdx.x * 256 + tid;
    int v = (i < n) ? cnt[i] : 0;
    sb[tid] = v;
    __syncthreads();
    for (int off = 1; off < 256; off <<= 1) {
        int t = (tid >= off) ? sb[tid - off] : 0;
        __syncthreads();
        sb[tid] += t;
        __syncthreads();
    }
    if (i < n) {
        int e = boff + sb[tid] - v;
        rp[i] = e;
        cursor[i] = e;
    }
    if (blockIdx.x == gridDim.x - 1 && tid == 255) rp[n] = boff + sb[255];
}

// ---------------------------------------------------------------------------
// 3. scatter src (as ushort) into CSR order — 4 edges/thread, uint4 loads
// ---------------------------------------------------------------------------
__global__ __launch_bounds__(256) void scatter_kernel(const unsigned* __restrict__ ei32,
                                                      const int* __restrict__ flag,
                                                      int E, int* __restrict__ cursor,
                                                      unsigned short* __restrict__ ssrc) {
    int base = (blockIdx.x * 256 + threadIdx.x) * 4;
    if (base >= E) return;
    int is64 = *flag;
    if (base + 3 < E && (E & 3) == 0) {
        int s0, s1, s2, s3, d0, d1, d2, d3;
        if (is64) {
            uv4 sa = *(const uv4*)&ei32[2 * base];
            uv4 sbv = *(const uv4*)&ei32[2 * base + 4];
            uv4 da = *(const uv4*)&ei32[2 * (E + base)];
            uv4 db = *(const uv4*)&ei32[2 * (E + base) + 4];
            s0 = (int)sa[0]; s1 = (int)sa[2]; s2 = (int)sbv[0]; s3 = (int)sbv[2];
            d0 = (int)da[0]; d1 = (int)da[2]; d2 = (int)db[0]; d3 = (int)db[2];
        } else {
            uv4 sa = *(const uv4*)&ei32[base];
            uv4 da = *(const uv4*)&ei32[E + base];
            s0 = (int)sa[0]; s1 = (int)sa[1]; s2 = (int)sa[2]; s3 = (int)sa[3];
            d0 = (int)da[0]; d1 = (int)da[1]; d2 = (int)da[2]; d3 = (int)da[3];
        }
        int p0 = atomicAdd(&cursor[d0], 1);
        int p1 = atomicAdd(&cursor[d1], 1);
        int p2 = atomicAdd(&cursor[d2], 1);
        int p3 = atomicAdd(&cursor[d3], 1);
        ssrc[p0] = (unsigned short)s0;
        ssrc[p1] = (unsigned short)s1;
        ssrc[p2] = (unsigned short)s2;
        ssrc[p3] = (unsigned short)s3;
    } else {
        for (int e = base; e < E && e < base + 4; ++e) {
            int s = is64 ? (int)ei32[2 * e] : (int)ei32[e];
            int d = is64 ? (int)ei32[2 * (E + e)] : (int)ei32[E + e];
            int pos = atomicAdd(&cursor[d], 1);
            ssrc[pos] = (unsigned short)s;
        }
    }
}

// ---------------------------------------------------------------------------
// 4a. aggregation (bf16 rows): wave per node.
//     lane = (slot r 0..7, chunk c 0..7); 16B bf16x8 load per lane -> 8 edges
//     per instruction, x2 unroll = 16 outstanding. shfl_xor reduce over r.
// ---------------------------------------------------------------------------
__global__ __launch_bounds__(256) void agg_kernel(const unsigned short* __restrict__ xb,
                                                  const int* __restrict__ rp,
                                                  const unsigned short* __restrict__ ssrc,
                                                  float* __restrict__ agg, int n) {
    int gw = (blockIdx.x * 256 + threadIdx.x) >> 6;
    if (gw >= n) return;
    int lane = threadIdx.x & 63;
    int r = lane >> 3;   // edge slot 0..7
    int c = lane & 7;    // bf16x8 chunk 0..7
    int beg = rp[gw], end = rp[gw + 1];
    float acc[8] = {0.f, 0.f, 0.f, 0.f, 0.f, 0.f, 0.f, 0.f};
    int e = beg + r;
    for (; e + 8 < end; e += 16) {
        int s0 = ssrc[e];
        int s1 = ssrc[e + 8];
        uv4 v0 = *(const uv4*)(xb + (size_t)s0 * 64 + c * 8);
        uv4 v1 = *(const uv4*)(xb + (size_t)s1 * 64 + c * 8);
#pragma unroll
        for (int q = 0; q < 4; ++q) {
            unsigned w0 = v0[q], w1 = v1[q];
            acc[2 * q]     += __builtin_bit_cast(float, w0 << 16);
            acc[2 * q + 1] += __builtin_bit_cast(float, w0 & 0xffff0000u);
            acc[2 * q]     += __builtin_bit_cast(float, w1 << 16);
            acc[2 * q + 1] += __builtin_bit_cast(float, w1 & 0xffff0000u);
        }
    }
    if (e < end) {
        int s0 = ssrc[e];
        uv4 v0 = *(const uv4*)(xb + (size_t)s0 * 64 + c * 8);
#pragma unroll
        for (int q = 0; q < 4; ++q) {
            unsigned w0 = v0[q];
            acc[2 * q]     += __builtin_bit_cast(float, w0 << 16);
            acc[2 * q + 1] += __builtin_bit_cast(float, w0 & 0xffff0000u);
        }
    }
#pragma unroll
    for (int j = 0; j < 8; ++j) {
        float t = acc[j];
        t += __shfl_xor(t, 8);
        t += __shfl_xor(t, 16);
        t += __shfl_xor(t, 32);
        acc[j] = t;
    }
    if (r == 0) {
        int deg = end - beg;
        float inv = 1.0f / (float)(deg > 1 ? deg : 1);
        f4 o0 = {acc[0] * inv, acc[1] * inv, acc[2] * inv, acc[3] * inv};
        f4 o1 = {acc[4] * inv, acc[5] * inv, acc[6] * inv, acc[7] * inv};
        *(f4*)&agg[gw * 64 + c * 8] = o0;
        *(f4*)&agg[gw * 64 + c * 8 + 4] = o1;
    }
}

// ---------------------------------------------------------------------------
// 4b. linear: out[n][o] = agg[n].Wl[o] + x[n].Wr[o] + bl[o] (+relu)
//     lane o holds Wl[o], Wr[o] in VGPRs; features broadcast via v_readlane
//     (VALU->SGPR, no LDS pipe). Optionally writes a bf16 copy for next agg.
// ---------------------------------------------------------------------------
template <bool RELU, bool WRITE_B>
__global__ __launch_bounds__(256) void lin_kernel(const float* __restrict__ aggp,
                                                  const float* __restrict__ xin,
                                                  const float* __restrict__ Wl,
                                                  const float* __restrict__ bl,
                                                  const float* __restrict__ Wr,
                                                  float* __restrict__ out,
                                                  unsigned short* __restrict__ outb, int n) {
    int lane = threadIdx.x & 63;
    f4 wl[16], wr[16];
#pragma unroll
    for (int k = 0; k < 16; ++k) {
        wl[k] = *(const f4*)&Wl[lane * 64 + k * 4];
        wr[k] = *(const f4*)&Wr[lane * 64 + k * 4];
    }
    float b = bl[lane];
    int gw = (blockIdx.x * 256 + threadIdx.x) >> 6;
    int nw = gridDim.x * 4;
    for (int node = gw; node < n; node += nw) {
        int ai = __builtin_bit_cast(int, aggp[node * 64 + lane]);
        int xi = __builtin_bit_cast(int, xin[node * 64 + lane]);
        float accl0 = 0.f, accl1 = 0.f, accr0 = 0.f, accr1 = 0.f;
#pragma unroll
        for (int k = 0; k < 64; k += 2) {
            float a0 = __builtin_bit_cast(float, __builtin_amdgcn_readlane(ai, k));
            float x0 = __builtin_bit_cast(float, __builtin_amdgcn_readlane(xi, k));
            float a1 = __builtin_bit_cast(float, __builtin_amdgcn_readlane(ai, k + 1));
            float x1 = __builtin_bit_cast(float, __builtin_amdgcn_readlane(xi, k + 1));
            accl0 = fmaf(a0, wl[k >> 2][k & 3], accl0);
            accr0 = fmaf(x0, wr[k >> 2][k & 3], accr0);
            accl1 = fmaf(a1, wl[(k + 1) >> 2][(k + 1) & 3], accl1);
            accr1 = fmaf(x1, wr[(k + 1) >> 2][(k + 1) & 3], accr1);
        }
        float res = (accl0 + accl1) + (accr0 + accr1) + b;
        if (RELU) res = fmaxf(res, 0.f);
        out[node * 64 + lane] = res;
        if (WRITE_B) outb[node * 64 + lane] = f2bf(res);
    }
}

// ---------------------------------------------------------------------------
extern "C" void kernel_launch(void* const* d_in, const int* in_sizes, int n_in,
                              void* d_out, int out_size, void* d_ws, size_t ws_size,
                              hipStream_t stream) {
    const float* x      = (const float*)d_in[0];
    const unsigned* ei  = (const unsigned*)d_in[1];
    const float* Wl0    = (const float*)d_in[2];
    const float* bl0    = (const float*)d_in[3];
    const float* Wr0    = (const float*)d_in[4];
    const float* Wl1    = (const float*)d_in[5];
    const float* bl1    = (const float*)d_in[6];
    const float* Wr1    = (const float*)d_in[7];
    float* out          = (float*)d_out;

    const int N = N_NODES;
    const int E = in_sizes[1] / 2;
    const int NB = (N + 255) / 256;   // 196 scan blocks (must be <= 256)

    char* w = (char*)d_ws;
    size_t used = 0;
    auto take = [&](size_t bytes) {
        char* p = w;
        size_t a = (bytes + 255) & ~(size_t)255;
        w += a; used += a;
        return p;
    };
    int*            flag   = (int*)take(sizeof(int));
    int*            cnt    = (int*)take((size_t)N * sizeof(int));
    int*            rp     = (int*)take((size_t)(N + 1) * sizeof(int));
    int*            cursor = (int*)take((size_t)N * sizeof(int));
    unsigned short* ssrc   = (unsigned short*)take((size_t)E * sizeof(unsigned short));
    int*            bsum   = (int*)take((size_t)NB * sizeof(int));
    float*          agg    = (float*)take((size_t)N * D * sizeof(float));
    unsigned short* xb0    = (unsigned short*)take((size_t)N * D * sizeof(unsigned short));
    unsigned short* h0b    = (unsigned short*)take((size_t)N * D * sizeof(unsigned short));
    // h0 f32: prefer workspace; fall back in-place into d_out (row-wise safe)
    float* h0;
    if (used + (size_t)N * D * sizeof(float) <= ws_size) {
        h0 = (float*)take((size_t)N * D * sizeof(float));
    } else {
        h0 = out;
    }

    hipMemsetAsync(cnt, 0, (size_t)N * sizeof(int), stream);
    detect_kernel<<<1, 64, 0, stream>>>(ei, flag);
    cvt_kernel<<<(N * D / 4 + 255) / 256, 256, 0, stream>>>(x, xb0, N * D);
    hist_kernel<<<(E / 4 + 255) / 256, 256, 0, stream>>>(ei, flag, E, cnt);
    scan_partial<<<NB, 256, 0, stream>>>(cnt, bsum, N);
    scan_final<<<NB, 256, 0, stream>>>(cnt, bsum, rp, cursor, N, NB);
    scatter_kernel<<<(E / 4 + 255) / 256, 256, 0, stream>>>(ei, flag, E, cursor, ssrc);

    int aggBlocks = (N * 64 + 255) / 256;   // one wave per node
    agg_kernel<<<aggBlocks, 256, 0, stream>>>(xb0, rp, ssrc, agg, N);
    lin_kernel<true, true><<<1024, 256, 0, stream>>>(agg, x, Wl0, bl0, Wr0, h0, h0b, N);
    agg_kernel<<<aggBlocks, 256, 0, stream>>>(h0b, rp, ssrc, agg, N);
    lin_kernel<false, false><<<1024, 256, 0, stream>>>(agg, h0, Wl1, bl1, Wr1, out, nullptr, N);
}